// Round 1
// baseline (3959.953 us; speedup 1.0000x reference)
//
#include <hip/hip_runtime.h>
#include <math.h>

// Problem: B=256, T=2048, H=150. Sequential GRU recurrence with relu'd hidden
// and per-step scalar linear head.
//
// Mapping: 1 block per batch element (256 blocks -> 1 per CU), 512 threads.
// Thread j (< 450) owns W_hh row j in registers (fully unrolled static
// indexing). Hidden state h lives in LDS between steps; each wave pulls the
// whole h vector with ONE per-lane ds_read_b128 (lane l -> h[4l..4l+3]) and
// broadcasts elements via v_readlane into SGPRs feeding v_fmac.
// __launch_bounds__(512,2): cap 256 VGPRs -> 2 waves/SIMD -> exactly 1
// block/CU by VGPR pressure.

#define BB 256
#define TT 2048
#define HH 150
#define H3 450

__device__ __forceinline__ float rl(float v, int l) {
    return __uint_as_float(__builtin_amdgcn_readlane(__float_as_uint(v), l));
}

__global__ __launch_bounds__(512, 2) void gru_seq_kernel(
    const float* __restrict__ input,   // [B,T]
    const float* __restrict__ W_ih,    // [450,1]
    const float* __restrict__ W_hh,    // [450,150]
    const float* __restrict__ b_ih,    // [450]
    const float* __restrict__ b_hh,    // [450]
    const float* __restrict__ W_lin,   // [1,150]
    const float* __restrict__ b_lin,   // [1]
    float* __restrict__ out)           // [B,T]
{
    const int b    = blockIdx.x;
    const int tid  = threadIdx.x;
    const int lane = tid & 63;

    __shared__ float  xrow[TT];       // 8 KB: whole input row for this batch elem
    __shared__ float4 h4[64];         // h[0..149], padded with zeros to 256 floats
    __shared__ float  pre[H3 + 2];    // gh[j] = h . W_hh[j] + b_hh[j]
    __shared__ float  ypart[4];

    // ---- prologue -------------------------------------------------------
    // input row -> LDS (coalesced, 512 x float4 == 8 KB exactly)
    ((float4*)xrow)[tid] = ((const float4*)(input + (size_t)b * TT))[tid];

    if (tid < 64) h4[tid] = make_float4(0.f, 0.f, 0.f, 0.f);
    if (tid < 4)  ypart[tid] = 0.f;

    // per-thread W_hh row in registers; zero-init so the unguarded dot loop
    // is well-defined for tid >= 450 (their results are discarded).
    float w[152];
    #pragma unroll
    for (int k = 0; k < 152; ++k) w[k] = 0.f;
    float bhh = 0.f;
    if (tid < H3) {
        const float* wr = W_hh + tid * HH;
        #pragma unroll
        for (int k = 0; k < HH; ++k) w[k] = wr[k];
        bhh = b_hh[tid];
    }

    float wih_r = 0.f, wih_z = 0.f, wih_n = 0.f;
    float bih_r = 0.f, bih_z = 0.f, bih_n = 0.f, wlin = 0.f;
    if (tid < HH) {
        wih_r = W_ih[tid];          bih_r = b_ih[tid];
        wih_z = W_ih[HH + tid];     bih_z = b_ih[HH + tid];
        wih_n = W_ih[2 * HH + tid]; bih_n = b_ih[2 * HH + tid];
        wlin  = W_lin[tid];
    }
    const float blin = b_lin[0];
    float hreg = 0.f;                 // thread j's private copy of h[j]
    float* outb = out + (size_t)b * TT;

    __syncthreads();

    // ---- recurrence -----------------------------------------------------
    for (int t = 0; t < TT; ++t) {
        // phase 1: every wave pulls full h with one ds_read_b128, then
        // readlane-broadcast + fmac. Runs unguarded (all lanes defined).
        float4 hv = h4[lane];
        float a0 = 0.f, a1 = 0.f, a2 = 0.f, a3 = 0.f;
        #pragma unroll
        for (int q = 0; q < 38; ++q) {
            float hx = rl(hv.x, q);
            float hy = rl(hv.y, q);
            float hz = rl(hv.z, q);
            float hw = rl(hv.w, q);
            a0 = fmaf(hx, w[4 * q + 0], a0);
            a1 = fmaf(hy, w[4 * q + 1], a1);
            a2 = fmaf(hz, w[4 * q + 2], a2);
            a3 = fmaf(hw, w[4 * q + 3], a3);
        }
        if (tid < H3) pre[tid] = (a0 + a1) + (a2 + a3) + bhh;
        __syncthreads();

        // phase 2: gates + hidden update (threads 0..149)
        float yc = 0.f;
        if (tid < HH) {
            float x  = xrow[t];
            float gr = fmaf(x, wih_r, bih_r) + pre[tid];
            float gz = fmaf(x, wih_z, bih_z) + pre[HH + tid];
            float hn = pre[2 * HH + tid];
            float r  = 1.f / (1.f + __expf(-gr));
            float z  = 1.f / (1.f + __expf(-gz));
            float ta = fmaf(x, wih_n, bih_n) + r * hn;
            ta = fminf(fmaxf(ta, -15.f), 15.f);      // avoid inf/inf in tanh
            float e  = __expf(2.f * ta);
            float n  = (e - 1.f) / (e + 1.f);        // tanh(ta)
            float hnew = fmaf(z, hreg - n, n);       // (1-z)*n + z*h
            hnew = fmaxf(hnew, 0.f);                 // relu
            hreg = hnew;
            ((float*)h4)[tid] = hnew;
            yc = hnew * wlin;
        }
        // y = h_new . W_lin + b_lin  (reduce across waves 0..2)
        if (tid < 192) {
            #pragma unroll
            for (int off = 32; off >= 1; off >>= 1)
                yc += __shfl_down(yc, off, 64);
            if (lane == 0) ypart[tid >> 6] = yc;
        }
        __syncthreads();
        if (tid == 0) outb[t] = ypart[0] + ypart[1] + ypart[2] + blin;
    }
}

extern "C" void kernel_launch(void* const* d_in, const int* in_sizes, int n_in,
                              void* d_out, int out_size, void* d_ws, size_t ws_size,
                              hipStream_t stream) {
    const float* input = (const float*)d_in[0];
    const float* W_ih  = (const float*)d_in[1];
    const float* W_hh  = (const float*)d_in[2];
    const float* b_ih  = (const float*)d_in[3];
    const float* b_hh  = (const float*)d_in[4];
    const float* W_lin = (const float*)d_in[5];
    const float* b_lin = (const float*)d_in[6];
    float* out = (float*)d_out;

    gru_seq_kernel<<<dim3(BB), dim3(512), 0, stream>>>(
        input, W_ih, W_hh, b_ih, b_hh, W_lin, b_lin, out);
}

// Round 2
// 3885.448 us; speedup vs baseline: 1.0192x; 1.0192x over previous
//
#include <hip/hip_runtime.h>
#include <math.h>

// B=256, T=2048, H=150. Sequential GRU recurrence, relu'd hidden, scalar head.
// 1 block per batch element (256 blocks = 256 CUs), 512 threads.
// Thread j < 450 owns W_hh row j in TEN named ext_vector_type(16) SSA values
// (w0..w9) -- not an array, so it cannot be demoted to scratch (R1 fix: the
// float w[152] array was never promoted; VGPR_Count=92 proved scratch).
// h broadcast: one ds_read_b128 per wave (lane l -> h[4l..4l+3]) then
// v_readlane -> SGPR -> v_fmac. __launch_bounds__(512,2): 256-VGPR cap,
// 2 waves/SIMD, exactly 1 block/CU.

#define BB 256
#define TT 2048
#define HH 150
#define H3 450

typedef float v16 __attribute__((ext_vector_type(16)));

__device__ __forceinline__ float rl(float v, int l) {
    return __uint_as_float(__builtin_amdgcn_readlane(__float_as_uint(v), l));
}

__global__ __launch_bounds__(512, 2) void gru_seq_kernel(
    const float* __restrict__ input,   // [B,T]
    const float* __restrict__ W_ih,    // [450,1]
    const float* __restrict__ W_hh,    // [450,150]
    const float* __restrict__ b_ih,    // [450]
    const float* __restrict__ b_hh,    // [450]
    const float* __restrict__ W_lin,   // [1,150]
    const float* __restrict__ b_lin,   // [1]
    float* __restrict__ out)           // [B,T]
{
    const int b    = blockIdx.x;
    const int tid  = threadIdx.x;
    const int lane = tid & 63;

    __shared__ float  xrow[TT];       // 8 KB: whole input row
    __shared__ float4 h4[64];         // h[0..149] zero-padded to 256 floats
    __shared__ float  pre[H3 + 2];
    __shared__ float  ypart[4];

    // ---- prologue -------------------------------------------------------
    ((float4*)xrow)[tid] = ((const float4*)(input + (size_t)b * TT))[tid];
    if (tid < 64) h4[tid] = make_float4(0.f, 0.f, 0.f, 0.f);
    if (tid < 4)  ypart[tid] = 0.f;

    // W_hh row -> ten named v16 SSA values (never an alloca).
    v16 w0, w1, w2, w3, w4, w5, w6, w7, w8, w9;
#define ZV(V) { _Pragma("unroll") for (int k = 0; k < 16; ++k) V[k] = 0.f; }
    ZV(w0) ZV(w1) ZV(w2) ZV(w3) ZV(w4) ZV(w5) ZV(w6) ZV(w7) ZV(w8) ZV(w9)
    float bhh = 0.f;
    if (tid < H3) {
        const float* wr = W_hh + tid * HH;
#define LV(V, OFF, CNT) { _Pragma("unroll") for (int k = 0; k < CNT; ++k) V[k] = wr[(OFF) + k]; }
        LV(w0,   0, 16) LV(w1,  16, 16) LV(w2,  32, 16) LV(w3,  48, 16)
        LV(w4,  64, 16) LV(w5,  80, 16) LV(w6,  96, 16) LV(w7, 112, 16)
        LV(w8, 128, 16) LV(w9, 144,  6)
        bhh = b_hh[tid];
    }

    float wih_r = 0.f, wih_z = 0.f, wih_n = 0.f;
    float bih_r = 0.f, bih_z = 0.f, bih_n = 0.f, wlin = 0.f;
    if (tid < HH) {
        wih_r = W_ih[tid];          bih_r = b_ih[tid];
        wih_z = W_ih[HH + tid];     bih_z = b_ih[HH + tid];
        wih_n = W_ih[2 * HH + tid]; bih_n = b_ih[2 * HH + tid];
        wlin  = W_lin[tid];
    }
    const float blin = b_lin[0];
    float hreg = 0.f;
    float* outb = out + (size_t)b * TT;

    __syncthreads();

    // ---- recurrence -----------------------------------------------------
    for (int t = 0; t < TT; ++t) {
        // phase 1: h . W_hh[row].  hv lane q holds h[4q..4q+3]; readlane
        // broadcasts to SGPR feeding v_fmac against resident weight regs.
        float4 hv = h4[lane];
        float a0 = 0.f, a1 = 0.f, a2 = 0.f, a3 = 0.f;
#define D4(Q, V) { \
        float hx = rl(hv.x, Q), hy = rl(hv.y, Q), hz = rl(hv.z, Q), hw = rl(hv.w, Q); \
        a0 = fmaf(hx, V[(((Q) & 3) << 2) + 0], a0); \
        a1 = fmaf(hy, V[(((Q) & 3) << 2) + 1], a1); \
        a2 = fmaf(hz, V[(((Q) & 3) << 2) + 2], a2); \
        a3 = fmaf(hw, V[(((Q) & 3) << 2) + 3], a3); }
        D4( 0, w0) D4( 1, w0) D4( 2, w0) D4( 3, w0)
        D4( 4, w1) D4( 5, w1) D4( 6, w1) D4( 7, w1)
        D4( 8, w2) D4( 9, w2) D4(10, w2) D4(11, w2)
        D4(12, w3) D4(13, w3) D4(14, w3) D4(15, w3)
        D4(16, w4) D4(17, w4) D4(18, w4) D4(19, w4)
        D4(20, w5) D4(21, w5) D4(22, w5) D4(23, w5)
        D4(24, w6) D4(25, w6) D4(26, w6) D4(27, w6)
        D4(28, w7) D4(29, w7) D4(30, w7) D4(31, w7)
        D4(32, w8) D4(33, w8) D4(34, w8) D4(35, w8)
        D4(36, w9) D4(37, w9)
        if (tid < H3) pre[tid] = (a0 + a1) + (a2 + a3) + bhh;
        __syncthreads();

        // phase 2: gates + hidden update (threads 0..149)
        float yc = 0.f;
        if (tid < HH) {
            float x  = xrow[t];
            float gr = fmaf(x, wih_r, bih_r) + pre[tid];
            float gz = fmaf(x, wih_z, bih_z) + pre[HH + tid];
            float hn = pre[2 * HH + tid];
            float r  = 1.f / (1.f + __expf(-gr));
            float z  = 1.f / (1.f + __expf(-gz));
            float ta = fmaf(x, wih_n, bih_n) + r * hn;
            ta = fminf(fmaxf(ta, -15.f), 15.f);
            float e  = __expf(2.f * ta);
            float n  = (e - 1.f) / (e + 1.f);        // tanh
            float hnew = fmaf(z, hreg - n, n);       // (1-z)*n + z*h
            hnew = fmaxf(hnew, 0.f);                 // relu
            hreg = hnew;
            ((float*)h4)[tid] = hnew;
            yc = hnew * wlin;
        }
        if (tid < 192) {
            #pragma unroll
            for (int off = 32; off >= 1; off >>= 1)
                yc += __shfl_down(yc, off, 64);
            if (lane == 0) ypart[tid >> 6] = yc;
        }
        __syncthreads();
        if (tid == 0) outb[t] = ypart[0] + ypart[1] + ypart[2] + blin;
    }
}

extern "C" void kernel_launch(void* const* d_in, const int* in_sizes, int n_in,
                              void* d_out, int out_size, void* d_ws, size_t ws_size,
                              hipStream_t stream) {
    const float* input = (const float*)d_in[0];
    const float* W_ih  = (const float*)d_in[1];
    const float* W_hh  = (const float*)d_in[2];
    const float* b_ih  = (const float*)d_in[3];
    const float* b_hh  = (const float*)d_in[4];
    const float* W_lin = (const float*)d_in[5];
    const float* b_lin = (const float*)d_in[6];
    float* out = (float*)d_out;

    gru_seq_kernel<<<dim3(BB), dim3(512), 0, stream>>>(
        input, W_ih, W_hh, b_ih, b_hh, W_lin, b_lin, out);
}